// Round 3
// baseline (287.868 us; speedup 1.0000x reference)
//
#include <hip/hip_runtime.h>
#include <hip/hip_bf16.h>
#include <hip/hip_fp16.h>

// Problem constants
#define B_N 32
#define S_N 2048
#define E_N 256
#define H_N 256
#define K2_N 512            // 2E
#define N3_N 768            // 3H
#define M_N (B_N * S_N)     // 65536 rows
#define CCH 64              // scan chunks per sequence
#define LCH (S_N / CCH)     // 32 steps per chunk

typedef __hip_bfloat16 bf16;
typedef __attribute__((ext_vector_type(8))) short bf16x8s;
typedef __attribute__((ext_vector_type(4))) float f32x4;

#define BM 128
#define BN 128
#define BK 32

#define GLOBAL_AS __attribute__((address_space(1)))
#define LDS_AS    __attribute__((address_space(3)))

// R9 post-mortem: traffic fixed (WRITE 228->131MB ideal, FETCH 100->21MB,
// XCD swizzle works) but BANK_CONFLICT 0->40.9M: the epilogue ds_write_b16
// puts 2 lanes in the SAME DWORD of one bank (sub-dword writes don't merge,
// ~52 extra cyc/instr * 786k). Reads (8 distinct addr / 4-bank group, b128)
// match the conflict-free K-loop profile. R10: z/f staging re-laid as dword
// D[rowpair][col] packing rows (2k,2k+1) of one column -> lane packs its own
// j-pairs, 2x ds_write_b32, <=2 lanes/bank DISTINCT dwords (zero modeled
// conflict). Readers: b128 + 4x v_perm row-split + 2x 8B coalesced stores.
// fp32 o-path writes were already conflict-free (b32, 2-way distinct) - kept.
// Also fused convert_x+transpose_w into one launch (launch-gap reduction).

__device__ __forceinline__ float sigmoid_fast(float v) {
    return __builtin_amdgcn_rcpf(1.0f + __expf(-v));
}
__device__ __forceinline__ float tanh_fast(float v) {
    return 2.0f * __builtin_amdgcn_rcpf(1.0f + __expf(-2.0f * v)) - 1.0f;
}

// K0: fused x-convert (blocks 0..8191) + W-transpose (blocks 8192..8287).
__global__ __launch_bounds__(256) void prep(
    const float* __restrict__ x, bf16* __restrict__ xb,
    const float* __restrict__ W, bf16* __restrict__ Wt)
{
    const int bid = blockIdx.x;
    if (bid < 8192) {
        if (bid == 0 && threadIdx.x < 32) {
            bf16 z[8] = {};
            *(int4*)(xb - 256 + threadIdx.x * 8) = *(int4*)z;
        }
        size_t i = ((size_t)bid * 256 + threadIdx.x) * 8;
        float4 v0 = *(const float4*)(x + i);
        float4 v1 = *(const float4*)(x + i + 4);
        bf16 t[8];
        t[0] = __float2bfloat16(v0.x); t[1] = __float2bfloat16(v0.y);
        t[2] = __float2bfloat16(v0.z); t[3] = __float2bfloat16(v0.w);
        t[4] = __float2bfloat16(v1.x); t[5] = __float2bfloat16(v1.y);
        t[6] = __float2bfloat16(v1.z); t[7] = __float2bfloat16(v1.w);
        *(int4*)(xb + i) = *(int4*)t;
    } else {
        __shared__ bf16 tile[64][65];
        const int tb = bid - 8192;               // 0..95
        const int k0 = (tb & 7) * 64;            // 8 k-tiles
        const int n0 = (tb >> 3) * 64;           // 12 n-tiles
        const int t  = threadIdx.x;
        const int tr = t >> 6;
        const int tc = t & 63;
        #pragma unroll
        for (int p = 0; p < 16; ++p) {
            int kk = tr + p * 4;
            tile[kk][tc] = __float2bfloat16(W[(size_t)(k0 + kk) * N3_N + n0 + tc]);
        }
        __syncthreads();
        #pragma unroll
        for (int p = 0; p < 16; ++p) {
            int nn = tr + p * 4;
            Wt[(size_t)(n0 + nn) * K2_N + k0 + tc] = tile[tc][nn];
        }
    }
}

// K1: gates GEMM + bias + activation, LDS-staged coalesced epilogue.
__global__ __launch_bounds__(256) void gemm_act(
    const bf16* __restrict__ xb, const bf16* __restrict__ Wt,
    const float* __restrict__ bvec,
    bf16* __restrict__ Zp, __half* __restrict__ Fh, float* __restrict__ Oout)
{
    // 16 KiB staging, reused: K-loop tiles -> epilogue stage.
    __shared__ union SMem {
        struct { bf16 A[BM][BK]; bf16 B[BN][BK]; } t;
        uint  dd[16][128];     // 8KiB: z/f stage, dword = col's rows (2k,2k+1)
        float epf[32][128];    // 16KiB: fp32 o stage
    } sm;

    const int tid  = threadIdx.x;
    const int lane = tid & 63;
    const int wave = tid >> 6;
    const int wm   = (wave & 1) * 64;
    const int wn   = (wave >> 1) * 64;
    const int l15  = lane & 15;
    const int quad = lane >> 4;
    const int l4   = lane >> 2;      // chunk row 0..15
    const int q4   = lane & 3;       // k-quarter 0..3
    const int gq   = q4 ^ ((l4 >> 1) & 3);    // swizzled source slot (stage)
    const int swq  = quad ^ ((l15 >> 1) & 3); // swizzled slot (fragment read)

    // XCD-chunked swizzle: 3072 blocks = 8 XCDs x 384, n fastest in-chunk.
    const int wg    = blockIdx.x;
    const int s     = (wg & 7) * 384 + (wg >> 3);
    const int m_idx = s / 6;
    const int n_idx = s - m_idx * 6;
    const int r0    = m_idx * BM;
    const int n0    = n_idx * BN;
    const bool zfix = ((r0 & (S_N - 1)) == 0);  // block row 0 has s==0

    f32x4 acc[4][4] = {};

    for (int kt = 0; kt < K2_N / BK; ++kt) {
        const int k0 = kt * BK;
        const bool second = (k0 >= E_N);   // x_{t-1} half
        __syncthreads();
        #pragma unroll
        for (int cc = 0; cc < 2; ++cc) {
            int c   = wave + cc * 4;
            int row = c * 16 + l4;
            int rA  = r0 + row - (second ? 1 : 0);
            const bf16* ga = xb + (size_t)rA * E_N + (k0 & (E_N - 1)) + gq * 8;
            __builtin_amdgcn_global_load_lds(
                (const GLOBAL_AS void*)ga,
                (LDS_AS void*)&sm.t.A[c * 16][0], 16, 0, 0);
            const bf16* gb = Wt + (size_t)(n0 + row) * K2_N + k0 + gq * 8;
            __builtin_amdgcn_global_load_lds(
                (const GLOBAL_AS void*)gb,
                (LDS_AS void*)&sm.t.B[c * 16][0], 16, 0, 0);
        }
        __syncthreads();
        if (second && zfix) {
            if (tid < 4) {
                bf16 zz[8] = {};
                *(int4*)(&sm.t.A[0][tid * 8]) = *(int4*)zz;
            }
            __syncthreads();
        }
        bf16x8s a_frag[4], b_frag[4];
        #pragma unroll
        for (int mi = 0; mi < 4; ++mi)
            a_frag[mi] = *(const bf16x8s*)(&sm.t.A[wm + mi * 16 + l15][swq * 8]);
        #pragma unroll
        for (int ni = 0; ni < 4; ++ni)
            b_frag[ni] = *(const bf16x8s*)(&sm.t.B[wn + ni * 16 + l15][swq * 8]);
        #pragma unroll
        for (int mi = 0; mi < 4; ++mi)
            #pragma unroll
            for (int ni = 0; ni < 4; ++ni)
                acc[mi][ni] = __builtin_amdgcn_mfma_f32_16x16x32_bf16(
                    a_frag[mi], b_frag[ni], acc[mi][ni], 0, 0, 0);
    }

    // --- epilogue ---
    // D map: row = r0+wm+mi*16+quad*4+j, col = n0+wn+ni*16+l15 (R6-verified).
    const int type  = n0 >> 8;          // 0=z(tanh,bf16) 1=f(sig,half) 2=o(sig,f32)
    const int cbase = n0 - type * 256;  // 0 or 128 within the 256-wide gate
    float bias[4];
    #pragma unroll
    for (int ni = 0; ni < 4; ++ni)
        bias[ni] = bvec[n0 + wn + ni * 16 + l15];

    const int wm8 = (wave & 1) * 8;     // rowpair base (0 | 8)
    #pragma unroll
    for (int mi = 0; mi < 4; ++mi) {
        __syncthreads();   // previous use of sm done
        if (type < 2) {
            // Stage: dword dd[rp][pcol] holds rows (2rp, 2rp+1) of col pcol.
            // pcol = col ^ (quad<<4): bank = pcol%32 -> quads split by parity
            // into 16-bank halves, 2 lanes/bank, DISTINCT dwords (rp differs).
            #pragma unroll
            for (int ni = 0; ni < 4; ++ni) {
                int pcol = (wn + ni * 16 + l15) ^ (quad << 4);
                float v0 = acc[mi][ni][0] + bias[ni];
                float v1 = acc[mi][ni][1] + bias[ni];
                float v2 = acc[mi][ni][2] + bias[ni];
                float v3 = acc[mi][ni][3] + bias[ni];
                uint pk01, pk23;
                if (type == 0) {
                    bf16 a0 = __float2bfloat16(tanh_fast(v0));
                    bf16 a1 = __float2bfloat16(tanh_fast(v1));
                    bf16 a2 = __float2bfloat16(tanh_fast(v2));
                    bf16 a3 = __float2bfloat16(tanh_fast(v3));
                    pk01 = (uint)*(ushort*)&a0 | ((uint)*(ushort*)&a1 << 16);
                    pk23 = (uint)*(ushort*)&a2 | ((uint)*(ushort*)&a3 << 16);
                } else {
                    __half a0 = __float2half(sigmoid_fast(v0));
                    __half a1 = __float2half(sigmoid_fast(v1));
                    __half a2 = __float2half(sigmoid_fast(v2));
                    __half a3 = __float2half(sigmoid_fast(v3));
                    pk01 = (uint)*(ushort*)&a0 | ((uint)*(ushort*)&a1 << 16);
                    pk23 = (uint)*(ushort*)&a2 | ((uint)*(ushort*)&a3 << 16);
                }
                sm.dd[wm8 + 2 * quad + 0][pcol] = pk01;   // rows j=0,1
                sm.dd[wm8 + 2 * quad + 1][pcol] = pk23;   // rows j=2,3
            }
            __syncthreads();
            // Read b128 (4 cols x rowpair), v_perm row-split, 2x 8B stores.
            #pragma unroll
            for (int it = 0; it < 2; ++it) {
                int cid = tid + it * 256;
                int rp  = cid >> 5;           // 0..15
                int cg  = cid & 31;           // 4-col group
                int qh  = (rp >> 1) & 3;      // writer quad
                const uint* src = &sm.dd[rp][4 * (cg ^ (qh << 2))];
                uint d0 = src[0], d1 = src[1], d2 = src[2], d3 = src[3];
                uint e0 = __builtin_amdgcn_perm(d1, d0, 0x05040100u); // even row
                uint e1 = __builtin_amdgcn_perm(d3, d2, 0x05040100u);
                uint o0 = __builtin_amdgcn_perm(d1, d0, 0x07060302u); // odd row
                uint o1 = __builtin_amdgcn_perm(d3, d2, 0x07060302u);
                int r  = 2 * rp;
                int g0 = r0 + ((r & 16) << 2) + mi * 16 + (r & 15);
                int g1 = g0 + 1;
                uint2 ve = make_uint2(e0, e1);
                uint2 vo = make_uint2(o0, o1);
                if (type == 0) {
                    *(uint2*)(Zp + (size_t)g0 * H_N + cbase + 4 * cg) = ve;
                    *(uint2*)(Zp + (size_t)g1 * H_N + cbase + 4 * cg) = vo;
                } else {
                    *(uint2*)(Fh + (size_t)g0 * H_N + cbase + 4 * cg) = ve;
                    *(uint2*)(Fh + (size_t)g1 * H_N + cbase + 4 * cg) = vo;
                }
            }
        } else {
            // fp32 o-gate: R9 scheme (writes already <=2-way distinct-dword).
            const int lrb = (wm >> 2) + quad * 4;
            #pragma unroll
            for (int ni = 0; ni < 4; ++ni) {
                int pc = (wn + ni * 16 + l15) ^ (quad << 4);
                #pragma unroll
                for (int j = 0; j < 4; ++j) {
                    float v = acc[mi][ni][j] + bias[ni];
                    sm.epf[lrb + j][pc] = sigmoid_fast(v);
                }
            }
            __syncthreads();
            #pragma unroll
            for (int it = 0; it < 4; ++it) {
                int cid = tid + it * 256;
                int row = cid >> 5;
                int ch  = cid & 31;
                int g   = (row >> 2) & 3;
                float4 vv = *(const float4*)&sm.epf[row][(ch ^ (g << 2)) * 4];
                int gr  = r0 + ((row & 16) << 2) + mi * 16 + (row & 15);
                *(float4*)(Oout + (size_t)gr * H_N + cbase + ch * 4) = vv;
            }
        }
    }
}

// K2: per-chunk local scan from c=0
__global__ __launch_bounds__(256) void scan_part1(
    const bf16* __restrict__ Zp, const __half* __restrict__ Fh,
    float* __restrict__ Cend, float* __restrict__ Pprod)
{
    int bc = blockIdx.x;
    int h  = threadIdx.x;
    size_t base = (size_t)bc * LCH * H_N + h;
    float c = 0.f, P = 1.f;
    for (int t = 0; t < LCH; ++t) {
        float z = __bfloat162float(Zp[base]);
        float f = __half2float(Fh[base]);
        c = f * c + (1.f - f) * z;
        P *= f;
        base += H_N;
    }
    Cend[(size_t)bc * H_N + h]  = c;
    Pprod[(size_t)bc * H_N + h] = P;
}

// K3: sequential scan across chunks
__global__ __launch_bounds__(256) void scan_part2(
    const float* __restrict__ Cend, const float* __restrict__ Pprod,
    float* __restrict__ Cstart)
{
    int b = blockIdx.x;
    int h = threadIdx.x;
    float cs = 0.f;
    for (int ch = 0; ch < CCH; ++ch) {
        size_t idx = (size_t)(b * CCH + ch) * H_N + h;
        Cstart[idx] = cs;
        cs = Cend[idx] + Pprod[idx] * cs;
    }
}

// K4: replay chunk; o staged fp32 in outH, overwritten with fp32 h in-place.
__global__ __launch_bounds__(256) void scan_part3(
    const bf16* __restrict__ Zp, const __half* __restrict__ Fh,
    const float* __restrict__ Cstart, const int* __restrict__ mask,
    float* __restrict__ outH, float* __restrict__ outHid, float* __restrict__ outCell)
{
    int bc = blockIdx.x;
    int b  = bc / CCH;
    int h  = threadIdx.x;
    float c = Cstart[(size_t)bc * H_N + h];
    int tgt = mask[b] - 1;
    tgt = (tgt < 0) ? 0 : ((tgt > S_N - 1) ? (S_N - 1) : tgt);
    int s0 = (bc & (CCH - 1)) * LCH;
    size_t base = (size_t)bc * LCH * H_N + h;
    for (int t = 0; t < LCH; ++t) {
        float z = __bfloat162float(Zp[base]);
        float f = __half2float(Fh[base]);
        float o = outH[base];
        c = f * c + (1.f - f) * z;
        float hv = o * c;
        outH[base] = hv;
        if (s0 + t == tgt) {
            outHid[(size_t)b * H_N + h]  = hv;
            outCell[(size_t)b * H_N + h] = c;
        }
        base += H_N;
    }
}

extern "C" void kernel_launch(void* const* d_in, const int* in_sizes, int n_in,
                              void* d_out, int out_size, void* d_ws, size_t ws_size,
                              hipStream_t stream) {
    const float* x = nullptr; const int* mask = nullptr;
    const float* W = nullptr; const float* bvec = nullptr;
    for (int i = 0; i < n_in; ++i) {
        switch (in_sizes[i]) {
            case M_N * E_N:     x    = (const float*)d_in[i]; break;
            case B_N:           mask = (const int*)d_in[i]; break;
            case K2_N * N3_N:   W    = (const float*)d_in[i]; break;
            case N3_N:          bvec = (const float*)d_in[i]; break;
        }
    }

    float* out     = (float*)d_out;
    float* outHid  = out + (size_t)M_N * H_N;
    float* outCell = outHid + (size_t)B_N * H_N;

    bf16*   xb = (bf16*)d_ws + 256;
    bf16*   Wt = xb + (size_t)M_N * E_N;
    bf16*   Zp = Wt + (size_t)N3_N * K2_N;
    __half* Fh = (__half*)(Zp + (size_t)M_N * H_N);
    float* Cend   = (float*)(Fh + (size_t)M_N * H_N);
    float* Pprod  = Cend + (size_t)B_N * CCH * H_N;
    float* Cstart = Pprod + (size_t)B_N * CCH * H_N;

    prep<<<8192 + 96, 256, 0, stream>>>(x, xb, W, Wt);

    gemm_act<<<(M_N / BM) * (N3_N / BN), 256, 0, stream>>>(xb, Wt, bvec, Zp, Fh, out);
    scan_part1<<<B_N * CCH, 256, 0, stream>>>(Zp, Fh, Cend, Pprod);
    scan_part2<<<B_N, 256, 0, stream>>>(Cend, Pprod, Cstart);
    scan_part3<<<B_N * CCH, 256, 0, stream>>>(Zp, Fh, Cstart, mask, out, outHid, outCell);
}

// Round 4
// 241.151 us; speedup vs baseline: 1.1937x; 1.1937x over previous
//
#include <hip/hip_runtime.h>
#include <hip/hip_bf16.h>
#include <hip/hip_fp16.h>

// Problem constants
#define B_N 32
#define S_N 2048
#define E_N 256
#define H_N 256
#define K2_N 512            // 2E
#define N3_N 768            // 3H
#define M_N (B_N * S_N)     // 65536 rows
#define CCH 64              // scan chunks per sequence
#define LCH (S_N / CCH)     // 32 steps per chunk

typedef __hip_bfloat16 bf16;
typedef __attribute__((ext_vector_type(8))) short bf16x8s;
typedef __attribute__((ext_vector_type(4))) float f32x4;

#define BM 128
#define BN 128
#define BK 32

#define GLOBAL_AS __attribute__((address_space(1)))
#define LDS_AS    __attribute__((address_space(3)))

// R10 post-mortem: BANK_CONFLICT identical (4.089e7) across R9/R10 despite
// different write layouts -> LDS-epilogue round-trip itself is the 40M-cycle
// cost (reads isomorphic in both rounds); my write-port model was wrong twice.
// R11: delete the staging entirely. SWAP MFMA OPERANDS (mfma(W,x) instead of
// mfma(x,W)) -> D transposed (bit-identical math): lane now owns 4 CONSECUTIVE
// W-cols of one x-row per (mi,ni) -> direct uint2 (z/f) / float4 (o) stores,
// 16/thread, no LDS, no syncs. Per-instr 32B runs per row; 4 adjacent ni
// instrs cover 128B contiguous -> L2 sector merge keeps WRITE near ideal.
// Keep: T2 K-loop swizzle (0 conflicts R8), XCD chunking (FETCH 100->21MB),
// rcp activations, fused prep, CCH=64 scans.

__device__ __forceinline__ float sigmoid_fast(float v) {
    return __builtin_amdgcn_rcpf(1.0f + __expf(-v));
}
__device__ __forceinline__ float tanh_fast(float v) {
    return 2.0f * __builtin_amdgcn_rcpf(1.0f + __expf(-2.0f * v)) - 1.0f;
}

// K0: fused x-convert (blocks 0..8191) + W-transpose (blocks 8192..8287).
__global__ __launch_bounds__(256) void prep(
    const float* __restrict__ x, bf16* __restrict__ xb,
    const float* __restrict__ W, bf16* __restrict__ Wt)
{
    const int bid = blockIdx.x;
    if (bid < 8192) {
        if (bid == 0 && threadIdx.x < 32) {
            bf16 z[8] = {};
            *(int4*)(xb - 256 + threadIdx.x * 8) = *(int4*)z;
        }
        size_t i = ((size_t)bid * 256 + threadIdx.x) * 8;
        float4 v0 = *(const float4*)(x + i);
        float4 v1 = *(const float4*)(x + i + 4);
        bf16 t[8];
        t[0] = __float2bfloat16(v0.x); t[1] = __float2bfloat16(v0.y);
        t[2] = __float2bfloat16(v0.z); t[3] = __float2bfloat16(v0.w);
        t[4] = __float2bfloat16(v1.x); t[5] = __float2bfloat16(v1.y);
        t[6] = __float2bfloat16(v1.z); t[7] = __float2bfloat16(v1.w);
        *(int4*)(xb + i) = *(int4*)t;
    } else {
        __shared__ bf16 tile[64][65];
        const int tb = bid - 8192;               // 0..95
        const int k0 = (tb & 7) * 64;            // 8 k-tiles
        const int n0 = (tb >> 3) * 64;           // 12 n-tiles
        const int t  = threadIdx.x;
        const int tr = t >> 6;
        const int tc = t & 63;
        #pragma unroll
        for (int p = 0; p < 16; ++p) {
            int kk = tr + p * 4;
            tile[kk][tc] = __float2bfloat16(W[(size_t)(k0 + kk) * N3_N + n0 + tc]);
        }
        __syncthreads();
        #pragma unroll
        for (int p = 0; p < 16; ++p) {
            int nn = tr + p * 4;
            Wt[(size_t)(n0 + nn) * K2_N + k0 + tc] = tile[tc][nn];
        }
    }
}

// K1: gates GEMM + bias + activation. Swapped-operand MFMA -> direct stores.
__global__ __launch_bounds__(256) void gemm_act(
    const bf16* __restrict__ xb, const bf16* __restrict__ Wt,
    const float* __restrict__ bvec,
    bf16* __restrict__ Zp, __half* __restrict__ Fh, float* __restrict__ Oout)
{
    __shared__ bf16 As[BM][BK];   // unpadded: global_load_lds lane-contiguous dest
    __shared__ bf16 Bs[BN][BK];

    const int tid  = threadIdx.x;
    const int lane = tid & 63;
    const int wave = tid >> 6;
    const int wm   = (wave & 1) * 64;
    const int wn   = (wave >> 1) * 64;
    const int l15  = lane & 15;
    const int quad = lane >> 4;
    const int l4   = lane >> 2;      // chunk row 0..15
    const int q4   = lane & 3;       // k-quarter 0..3
    const int gq   = q4 ^ ((l4 >> 1) & 3);    // swizzled source slot (stage)
    const int swq  = quad ^ ((l15 >> 1) & 3); // swizzled slot (fragment read)

    // XCD-chunked swizzle: 3072 blocks = 8 XCDs x 384, n fastest in-chunk.
    const int wg    = blockIdx.x;
    const int s     = (wg & 7) * 384 + (wg >> 3);
    const int m_idx = s / 6;
    const int n_idx = s - m_idx * 6;
    const int r0    = m_idx * BM;
    const int n0    = n_idx * BN;
    const bool zfix = ((r0 & (S_N - 1)) == 0);  // block row 0 has s==0

    f32x4 acc[4][4] = {};

    for (int kt = 0; kt < K2_N / BK; ++kt) {
        const int k0 = kt * BK;
        const bool second = (k0 >= E_N);   // x_{t-1} half
        __syncthreads();
        #pragma unroll
        for (int cc = 0; cc < 2; ++cc) {
            int c   = wave + cc * 4;
            int row = c * 16 + l4;
            int rA  = r0 + row - (second ? 1 : 0);
            const bf16* ga = xb + (size_t)rA * E_N + (k0 & (E_N - 1)) + gq * 8;
            __builtin_amdgcn_global_load_lds(
                (const GLOBAL_AS void*)ga,
                (LDS_AS void*)&As[c * 16][0], 16, 0, 0);
            const bf16* gb = Wt + (size_t)(n0 + row) * K2_N + k0 + gq * 8;
            __builtin_amdgcn_global_load_lds(
                (const GLOBAL_AS void*)gb,
                (LDS_AS void*)&Bs[c * 16][0], 16, 0, 0);
        }
        __syncthreads();
        if (second && zfix) {
            // global row r0 has s==0: x_prev must be zero. Row 0's slot
            // swizzle f(0)==0 so a linear zero-fill is correct.
            if (tid < 4) {
                bf16 zz[8] = {};
                *(int4*)(&As[0][tid * 8]) = *(int4*)zz;
            }
            __syncthreads();
        }
        bf16x8s a_frag[4], b_frag[4];
        #pragma unroll
        for (int mi = 0; mi < 4; ++mi)
            a_frag[mi] = *(const bf16x8s*)(&As[wm + mi * 16 + l15][swq * 8]);
        #pragma unroll
        for (int ni = 0; ni < 4; ++ni)
            b_frag[ni] = *(const bf16x8s*)(&Bs[wn + ni * 16 + l15][swq * 8]);
        // SWAPPED operands: D^T layout. Lane owns x-row (col dim = l15),
        // W-cols quad*4+j (row dim). Bit-identical element values.
        #pragma unroll
        for (int mi = 0; mi < 4; ++mi)
            #pragma unroll
            for (int ni = 0; ni < 4; ++ni)
                acc[mi][ni] = __builtin_amdgcn_mfma_f32_16x16x32_bf16(
                    b_frag[ni], a_frag[mi], acc[mi][ni], 0, 0, 0);
    }

    // --- epilogue: direct stores, no LDS ---
    // After swap: acc[mi][ni][j] = D[row = r0+wm+mi*16+l15]
    //                               [col = n0+wn+ni*16+quad*4+j]
    const int type  = n0 >> 8;          // 0=z(tanh,bf16) 1=f(sig,half) 2=o(sig,f32)
    const int cbase = n0 + wn - type * 256 + quad * 4;
    float4 bias4[4];
    #pragma unroll
    for (int ni = 0; ni < 4; ++ni)
        bias4[ni] = *(const float4*)&bvec[n0 + wn + ni * 16 + quad * 4];

    #pragma unroll
    for (int mi = 0; mi < 4; ++mi) {
        const size_t gr = (size_t)(r0 + wm + mi * 16 + l15) * H_N;
        #pragma unroll
        for (int ni = 0; ni < 4; ++ni) {
            const int col = cbase + ni * 16;
            float v0 = acc[mi][ni][0] + bias4[ni].x;
            float v1 = acc[mi][ni][1] + bias4[ni].y;
            float v2 = acc[mi][ni][2] + bias4[ni].z;
            float v3 = acc[mi][ni][3] + bias4[ni].w;
            if (type == 0) {
                bf16 a0 = __float2bfloat16(tanh_fast(v0));
                bf16 a1 = __float2bfloat16(tanh_fast(v1));
                bf16 a2 = __float2bfloat16(tanh_fast(v2));
                bf16 a3 = __float2bfloat16(tanh_fast(v3));
                uint2 pk;
                pk.x = (uint)*(ushort*)&a0 | ((uint)*(ushort*)&a1 << 16);
                pk.y = (uint)*(ushort*)&a2 | ((uint)*(ushort*)&a3 << 16);
                *(uint2*)(Zp + gr + col) = pk;
            } else if (type == 1) {
                __half a0 = __float2half(sigmoid_fast(v0));
                __half a1 = __float2half(sigmoid_fast(v1));
                __half a2 = __float2half(sigmoid_fast(v2));
                __half a3 = __float2half(sigmoid_fast(v3));
                uint2 pk;
                pk.x = (uint)*(ushort*)&a0 | ((uint)*(ushort*)&a1 << 16);
                pk.y = (uint)*(ushort*)&a2 | ((uint)*(ushort*)&a3 << 16);
                *(uint2*)(Fh + gr + col) = pk;
            } else {
                float4 vv = make_float4(sigmoid_fast(v0), sigmoid_fast(v1),
                                        sigmoid_fast(v2), sigmoid_fast(v3));
                *(float4*)(Oout + gr + col) = vv;
            }
        }
    }
}

// K2: per-chunk local scan from c=0
__global__ __launch_bounds__(256) void scan_part1(
    const bf16* __restrict__ Zp, const __half* __restrict__ Fh,
    float* __restrict__ Cend, float* __restrict__ Pprod)
{
    int bc = blockIdx.x;
    int h  = threadIdx.x;
    size_t base = (size_t)bc * LCH * H_N + h;
    float c = 0.f, P = 1.f;
    for (int t = 0; t < LCH; ++t) {
        float z = __bfloat162float(Zp[base]);
        float f = __half2float(Fh[base]);
        c = f * c + (1.f - f) * z;
        P *= f;
        base += H_N;
    }
    Cend[(size_t)bc * H_N + h]  = c;
    Pprod[(size_t)bc * H_N + h] = P;
}

// K3: sequential scan across chunks
__global__ __launch_bounds__(256) void scan_part2(
    const float* __restrict__ Cend, const float* __restrict__ Pprod,
    float* __restrict__ Cstart)
{
    int b = blockIdx.x;
    int h = threadIdx.x;
    float cs = 0.f;
    for (int ch = 0; ch < CCH; ++ch) {
        size_t idx = (size_t)(b * CCH + ch) * H_N + h;
        Cstart[idx] = cs;
        cs = Cend[idx] + Pprod[idx] * cs;
    }
}

// K4: replay chunk; o staged fp32 in outH, overwritten with fp32 h in-place.
__global__ __launch_bounds__(256) void scan_part3(
    const bf16* __restrict__ Zp, const __half* __restrict__ Fh,
    const float* __restrict__ Cstart, const int* __restrict__ mask,
    float* __restrict__ outH, float* __restrict__ outHid, float* __restrict__ outCell)
{
    int bc = blockIdx.x;
    int b  = bc / CCH;
    int h  = threadIdx.x;
    float c = Cstart[(size_t)bc * H_N + h];
    int tgt = mask[b] - 1;
    tgt = (tgt < 0) ? 0 : ((tgt > S_N - 1) ? (S_N - 1) : tgt);
    int s0 = (bc & (CCH - 1)) * LCH;
    size_t base = (size_t)bc * LCH * H_N + h;
    for (int t = 0; t < LCH; ++t) {
        float z = __bfloat162float(Zp[base]);
        float f = __half2float(Fh[base]);
        float o = outH[base];
        c = f * c + (1.f - f) * z;
        float hv = o * c;
        outH[base] = hv;
        if (s0 + t == tgt) {
            outHid[(size_t)b * H_N + h]  = hv;
            outCell[(size_t)b * H_N + h] = c;
        }
        base += H_N;
    }
}

extern "C" void kernel_launch(void* const* d_in, const int* in_sizes, int n_in,
                              void* d_out, int out_size, void* d_ws, size_t ws_size,
                              hipStream_t stream) {
    const float* x = nullptr; const int* mask = nullptr;
    const float* W = nullptr; const float* bvec = nullptr;
    for (int i = 0; i < n_in; ++i) {
        switch (in_sizes[i]) {
            case M_N * E_N:     x    = (const float*)d_in[i]; break;
            case B_N:           mask = (const int*)d_in[i]; break;
            case K2_N * N3_N:   W    = (const float*)d_in[i]; break;
            case N3_N:          bvec = (const float*)d_in[i]; break;
        }
    }

    float* out     = (float*)d_out;
    float* outHid  = out + (size_t)M_N * H_N;
    float* outCell = outHid + (size_t)B_N * H_N;

    bf16*   xb = (bf16*)d_ws + 256;
    bf16*   Wt = xb + (size_t)M_N * E_N;
    bf16*   Zp = Wt + (size_t)N3_N * K2_N;
    __half* Fh = (__half*)(Zp + (size_t)M_N * H_N);
    float* Cend   = (float*)(Fh + (size_t)M_N * H_N);
    float* Pprod  = Cend + (size_t)B_N * CCH * H_N;
    float* Cstart = Pprod + (size_t)B_N * CCH * H_N;

    prep<<<8192 + 96, 256, 0, stream>>>(x, xb, W, Wt);

    gemm_act<<<(M_N / BM) * (N3_N / BN), 256, 0, stream>>>(xb, Wt, bvec, Zp, Fh, out);
    scan_part1<<<B_N * CCH, 256, 0, stream>>>(Zp, Fh, Cend, Pprod);
    scan_part2<<<B_N, 256, 0, stream>>>(Cend, Pprod, Cstart);
    scan_part3<<<B_N * CCH, 256, 0, stream>>>(Zp, Fh, Cstart, mask, out, outHid, outCell);
}